// Round 14
// baseline (1188.485 us; speedup 1.0000x reference)
//
#include <hip/hip_runtime.h>
#include <hip/hip_bf16.h>
#include <math.h>

typedef unsigned int uint;
typedef unsigned long long u64;

#define BB 4
#define NN 100000
#define PRE 6000
#define POST 1000
#define NWRD 94          // 6000/64 rounded up
#define SCAP 8192        // bucketed capacity
#define ROWP 6016        // padded rows/cols
#define KSUP 64          // max suppressors tracked per box
#define NRANGE 32        // hist ranges per image (2048 bins each)
#define NBLK 512         // persistent grid: >=2 blocks/CU x 256 CUs co-resident
#define NT (NBLK * 256)

// ---- workspace layout (bytes) ----
constexpr size_t OFF_HDR   = 0;                                    // uints 0..7: t1[4], limit[4]
constexpr size_t OFF_RTOT  = 64;                                   // 128 uints: per-(b,range) totals
constexpr size_t OFF_BAR   = 576;                                  // 16 uints: barrier counters (memset per call)
constexpr size_t OFF_CNT   = 1024;                                 // BB*ROWP*4 (zeroed in phase A)
constexpr size_t OFF_H1    = OFF_CNT + (size_t)BB*ROWP*4;          // hist1: 1MB (fully overwritten)
constexpr size_t OFF_BASE  = OFF_H1  + (size_t)BB*65536*4;         // base:  1MB (fully overwritten)
constexpr size_t OFF_KEY   = OFF_BASE+ (size_t)BB*65536*4;         // keyhi: BB*NN*4
constexpr size_t OFF_BUCK  = OFF_KEY + (size_t)BB*NN*4;            // BB*SCAP*8
constexpr size_t OFF_LIST  = OFF_BUCK+ (size_t)BB*SCAP*8;          // BB*ROWP*KSUP*4
constexpr size_t OFF_BOX   = OFF_LIST+ (size_t)BB*ROWP*KSUP*4;
constexpr size_t OFF_SCO   = OFF_BOX + (size_t)BB*ROWP*16;
constexpr size_t OFF_AREA  = OFF_SCO + (size_t)BB*ROWP*4;
constexpr size_t OFF_VAL   = OFF_AREA+ (size_t)BB*ROWP*4;          // validW (zeroed in phase A)

__device__ __forceinline__ float clipf(float v, float hi) {
  return fminf(fmaxf(v, 0.0f), hi);
}

// Software grid barrier. Arrive = release fence + ONE device-scope RMW.
// Poll = device-scope atomic LOAD (coherent, L1-bypassing, non-serializing)
// + s_sleep backoff. Counters zeroed by hipMemsetAsync before launch; one
// counter per phase. All NBLK blocks are co-resident (512 blocks, <=10KB LDS,
// 256-thread blocks -> >=2 blocks/CU regardless of VGPR count).
__device__ __forceinline__ void gridbar(uint* bar, int ph) {
  __syncthreads();
  if (threadIdx.x == 0) {
    __threadfence();                            // release this block's writes
    atomicAdd(&bar[ph], 1u);
    while (__hip_atomic_load(&bar[ph], __ATOMIC_ACQUIRE,
                             __HIP_MEMORY_SCOPE_AGENT) < (uint)NBLK)
      __builtin_amdgcn_s_sleep(32);
  }
  __syncthreads();
  __threadfence();                              // acquire on all threads
}

// ---- phase A: keys (streaming) + zero cnt/validW ----
__device__ __attribute__((noinline))
void phaseA(const float4* props, const float2* clsp, uint* keyhi,
            uint* cnt, u64* validW) {
  int gtid = blockIdx.x * 256 + threadIdx.x;
  for (int idx = gtid; idx < BB * NN; idx += NT) {
    int b = idx / NN, i = idx - b * NN;
    float4 p = props[(size_t)b * NN + i];
    float x1 = clipf(p.x, 800.0f), y1 = clipf(p.y, 800.0f);
    float x2 = clipf(p.z, 800.0f), y2 = clipf(p.w, 800.0f);
    bool valid = ((x2 - x1) >= 16.0f) && ((y2 - y1) >= 16.0f);
    float s  = clsp[(size_t)b * NN + i].y;
    float sm = valid ? s : -INFINITY;
    uint u = __float_as_uint(sm);
    u = (u & 0x80000000u) ? ~u : (u | 0x80000000u);  // monotonic map
    keyhi[idx] = ~u;                                  // ascending key == DESC score
  }
  for (int idx = gtid; idx < BB * ROWP; idx += NT) cnt[idx] = 0u;
  if (gtid < BB * 96) validW[gtid] = 0ull;
}

// ---- phase B1: per-(image,range) LDS histogram -> hist1 + rtot ----
__device__ __attribute__((noinline))
void phaseB1(const uint* keyhi, uint* hist1, uint* rtot) {
  if (blockIdx.x >= BB * NRANGE) return;
  __shared__ uint lh[2048];
  __shared__ uint wr[4];
  int tid = threadIdx.x, lane = tid & 63, W = tid >> 6;
  int b = blockIdx.x >> 5, r = blockIdx.x & 31;
  uint lo = (uint)r << 11;
  for (int i = tid; i < 2048; i += 256) lh[i] = 0u;
  __syncthreads();
  const uint4* K = (const uint4*)keyhi + (size_t)b * (NN / 4);
  for (int i = tid; i < NN / 4; i += 256) {
    uint4 v = K[i];
    uint q0 = (v.x >> 16) - lo; if (q0 < 2048u) atomicAdd(&lh[q0], 1u);
    uint q1 = (v.y >> 16) - lo; if (q1 < 2048u) atomicAdd(&lh[q1], 1u);
    uint q2 = (v.z >> 16) - lo; if (q2 < 2048u) atomicAdd(&lh[q2], 1u);
    uint q3 = (v.w >> 16) - lo; if (q3 < 2048u) atomicAdd(&lh[q3], 1u);
  }
  __syncthreads();
  uint* H = hist1 + (size_t)b * 65536 + lo;
  uint s = 0;
  for (int i = tid; i < 2048; i += 256) { H[i] = lh[i]; s += lh[i]; }
  for (int off = 32; off > 0; off >>= 1) s += __shfl_xor(s, off);
  if (lane == 0) wr[W] = s;
  __syncthreads();
  if (tid == 0) rtot[b * 32 + r] = wr[0] + wr[1] + wr[2] + wr[3];
}

// ---- phase B2: per-range exclusive scan -> base[]; boundary -> hdr ----
__device__ __attribute__((noinline))
void phaseB2(const uint* hist1, const uint* rtot, uint* base, uint* hdr) {
  if (blockIdx.x >= BB * NRANGE) return;
  __shared__ uint wt[4];
  int tid = threadIdx.x, lane = tid & 63, W = tid >> 6;
  int b = blockIdx.x >> 5, r = blockIdx.x & 31;
  uint lo = (uint)r << 11;
  uint rbase = 0, tot = 0;
  for (int k = 0; k < 32; ++k) {
    uint v = rtot[b * 32 + k];
    if (k < r) rbase += v;
    if (k == r) tot = v;
  }
  const uint* h = hist1 + (size_t)b * 65536 + lo;
  uint c[8], s = 0;
  for (int k = 0; k < 8; ++k) { c[k] = h[tid * 8 + k]; s += c[k]; }
  uint ps = s;
  for (int off = 1; off < 64; off <<= 1) {
    uint v = __shfl_up(ps, off);
    if (lane >= off) ps += v;
  }
  if (lane == 63) wt[W] = ps;
  __syncthreads();
  uint wbase = 0;
  for (int k = 0; k < 4; ++k) { if (k < W) wbase += wt[k]; }
  uint excl = rbase + wbase + ps - s;     // global exclusive before thread's bins
  uint run = excl;
  uint* bs = base + (size_t)b * 65536 + lo;
  for (int k = 0; k < 8; ++k) { bs[tid * 8 + k] = run; run += c[k]; }
  // boundary bucket (cumulative position PRE); total over all ranges = NN > PRE
  if (rbase < (uint)PRE && (uint)PRE <= rbase + tot) {
    uint cc = excl;
    for (int k = 0; k < 8; ++k) {
      uint hv = c[k];
      if (cc < (uint)PRE && (uint)PRE <= cc + hv) {
        hdr[0 + b] = lo + (uint)(tid * 8 + k);   // t1 boundary bucket
        hdr[4 + b] = cc + hv;                    // limit = cumulative through t1
      }
      cc += hv;
    }
  }
}

// ---- phase D: bucket scatter ----
__device__ __attribute__((noinline))
void phaseD(const uint* keyhi, uint* base, const uint* hdr, u64* buck) {
  int gtid = blockIdx.x * 256 + threadIdx.x;
  for (int idx = gtid; idx < BB * NN; idx += NT) {
    int b = idx / NN;
    uint kh = keyhi[idx];
    if ((kh >> 16) <= hdr[0 + b]) {
      uint pos = atomicAdd(&base[(size_t)b * 65536 + (kh >> 16)], 1u);
      if (pos < SCAP) buck[(size_t)b * SCAP + pos] = ((u64)kh << 32) | (uint)(idx - b * NN);
    }
  }
}

// ---- phase E: exact rank -> direct scatter of box/score/area/validW ----
__device__ __attribute__((noinline))
void phaseE(const u64* buck, const uint* base, const uint* hist1, const uint* hdr,
            const float4* props, const float2* clsp,
            float4* boxes6k, float* score6k, float* area6k, u64* validW) {
  int gtid = blockIdx.x * 256 + threadIdx.x;
  if (gtid >= BB * SCAP) return;
  int b = gtid >> 13, sl = gtid & (SCAP - 1);
  uint limit = hdr[4 + b];
  if (sl >= (int)limit) return;
  u64 v = buck[(size_t)b * SCAP + sl];
  uint bkt = (uint)(v >> 48);
  uint cb_ = hist1[(size_t)b * 65536 + bkt];
  uint b0 = base[(size_t)b * 65536 + bkt] - cb_;   // restore pre-scatter base
  uint rk = b0;
  for (uint m = 0; m < cb_; ++m) {
    u64 w = buck[(size_t)b * SCAP + b0 + m];
    rk += (w < v) ? 1u : 0u;                       // (key,idx) stable order
  }
  if (rk >= (uint)PRE) return;
  uint idx2 = (uint)(v & 0xFFFFFFFFull);
  float4 p = props[(size_t)b * NN + idx2];
  float x1 = clipf(p.x, 800.0f), y1 = clipf(p.y, 800.0f);
  float x2 = clipf(p.z, 800.0f), y2 = clipf(p.w, 800.0f);
  float w = x2 - x1, h = y2 - y1;
  bool valid = (w >= 16.0f) && (h >= 16.0f);
  float4 bx; bx.x = x1; bx.y = y1; bx.z = x2; bx.w = y2;
  boxes6k[(size_t)b * ROWP + rk] = bx;
  score6k[(size_t)b * ROWP + rk] = clsp[(size_t)b * NN + idx2].y;
  area6k [(size_t)b * ROWP + rk] = fmaxf(w, 0.0f) * fmaxf(h, 0.0f);
  if (valid) atomicOr(&validW[(size_t)b * 96 + (rk >> 6)], 1ull << (rk & 63));
}

// ---- phase S: sup_build tiles, 4-col ILP (exact division-free IoU test:
// fl32(inter/un) > 0.7f <=> (double)inter >= mid*(double)un,
// mid = 0.7f + 2^-25 = 0x1.6666668p-1; 25b x 24b = 49 bits, exact) ----
__device__ __attribute__((noinline))
void phaseS(const float4* boxes6k, const float* area6k, const u64* validW,
            uint* cnt, uint* list) {
  __shared__ float4 rbox[64];
  __shared__ float  rar[64];
  int tid = threadIdx.x, lane = tid & 63, wv = tid >> 6;
  const int njobs = NWRD * 6 * BB;
  for (int job = blockIdx.x; job < njobs; job += NBLK) {
    int b = job & 3, rest = job >> 2;
    int cwb = rest % 6, gb = rest / 6;
    int cw0 = cwb * 16;
    __syncthreads();                        // protect LDS reuse across jobs
    if (tid < 64) {
      rbox[tid] = boxes6k[(size_t)b * ROWP + gb * 64 + tid];
      rar[tid]  = area6k [(size_t)b * ROWP + gb * 64 + tid];
    }
    __syncthreads();
    if (cw0 + 15 >= gb) {
      u64 vmask = validW[(size_t)b * 96 + gb];
      int    cw[4];
      u64    rowsel[4], bits[4];
      float4 cbox[4];
      float  carea[4];
      #pragma unroll
      for (int k = 0; k < 4; ++k) {
        cw[k] = cw0 + 4 * k + wv;
        int col = cw[k] * 64 + lane;
        int colc = col < (ROWP - 1) ? col : (ROWP - 1);
        cbox[k]  = boxes6k[(size_t)b * ROWP + colc];
        carea[k] = area6k [(size_t)b * ROWP + colc];
        rowsel[k] = (cw[k] > gb) ? vmask
                  : ((cw[k] == gb && lane) ? (vmask & ((1ull << lane) - 1ull)) : 0ull);
        bits[k] = 0ull;
      }
      const double M = 0x1.6666668p-1;
      #pragma unroll 4
      for (int rr = 0; rr < 64; ++rr) {
        float4 rb = rbox[rr];
        float  ra = rar[rr];
        #pragma unroll
        for (int k = 0; k < 4; ++k) {
          float xx1 = fmaxf(rb.x, cbox[k].x), yy1 = fmaxf(rb.y, cbox[k].y);
          float xx2 = fminf(rb.z, cbox[k].z), yy2 = fminf(rb.w, cbox[k].w);
          float inter = fmaxf(xx2 - xx1, 0.0f) * fmaxf(yy2 - yy1, 0.0f);
          float un = fmaxf(ra + carea[k] - inter, 1e-9f);
          bits[k] |= ((double)inter >= M * (double)un) ? (1ull << rr) : 0ull;
        }
      }
      int rbb = gb * 64;
      #pragma unroll
      for (int k = 0; k < 4; ++k) {
        if (cw[k] < NWRD) {
          u64 bt = bits[k] & rowsel[k];
          int col = cw[k] * 64 + lane;
          while (bt) {
            int r = __ffsll((long long)bt) - 1;
            bt &= bt - 1;
            uint pos = atomicAdd(&cnt[(size_t)b * ROWP + col], 1u);
            if (pos < KSUP) list[((size_t)b * ROWP + col) * KSUP + pos] = (uint)(rbb + r);
          }
        }
      }
    }
  }
}

// ---- fused pipeline ----
__global__ __launch_bounds__(256) void fused(const float4* __restrict__ props,
                                             const float2* __restrict__ clsp,
                                             uint* __restrict__ keyhi,
                                             uint* __restrict__ hist1,
                                             uint* __restrict__ base,
                                             uint* __restrict__ hdr,
                                             uint* __restrict__ rtot,
                                             uint* __restrict__ bar,
                                             u64*  __restrict__ buck,
                                             float4* __restrict__ boxes6k,
                                             float* __restrict__ score6k,
                                             float* __restrict__ area6k,
                                             u64*  __restrict__ validW,
                                             uint* __restrict__ cnt,
                                             uint* __restrict__ list) {
  phaseA(props, clsp, keyhi, cnt, validW);
  gridbar(bar, 0);
  phaseB1(keyhi, hist1, rtot);
  gridbar(bar, 1);
  phaseB2(hist1, rtot, base, hdr);
  gridbar(bar, 2);
  phaseD(keyhi, base, hdr, buck);
  gridbar(bar, 3);
  phaseE(buck, base, hist1, hdr, props, clsp, boxes6k, score6k, area6k, validW);
  gridbar(bar, 4);
  phaseS(boxes6k, area6k, validW, cnt, list);
}

// ---------- sparse Jacobi fixpoint resolve + fused finalize ----------
__global__ __launch_bounds__(1024) void sparse_resolve(const uint* __restrict__ cnt,
                                                       const uint* __restrict__ list,
                                                       const u64* __restrict__ validW,
                                                       const float* __restrict__ score6k,
                                                       const float4* __restrict__ boxes6k,
                                                       float* __restrict__ out) {
  int b = blockIdx.x, tid = threadIdx.x;
  __shared__ u64 ALIVE[96], DEC[96], VW[96];
  __shared__ int changed;
  if (tid < 96) {
    ALIVE[tid] = 0ull; DEC[tid] = 0ull;
    VW[tid] = validW[(size_t)b * 96 + tid];
  }
  __syncthreads();

  uint myCnt[6];
  #pragma unroll
  for (int r = 0; r < 6; ++r) {
    int j = tid + r * 1024;
    myCnt[r] = (j < PRE) ? cnt[(size_t)b * ROWP + j] : 0u;
  }
  #pragma unroll
  for (int r = 0; r < 6; ++r) {
    int j = tid + r * 1024;
    if (j >= PRE) continue;
    bool valid = (VW[j >> 6] >> (j & 63)) & 1ull;
    if (myCnt[r] == 0u || !valid) {
      atomicOr(&DEC[j >> 6], 1ull << (j & 63));
      if (valid) atomicOr(&ALIVE[j >> 6], 1ull << (j & 63));
    }
  }
  __syncthreads();

  while (true) {
    if (tid == 0) changed = 0;
    __syncthreads();
    int decJ[6]; bool decAlive[6];
    #pragma unroll
    for (int r = 0; r < 6; ++r) {
      decJ[r] = -1; decAlive[r] = false;
      int j = tid + r * 1024;
      if (j >= PRE || myCnt[r] == 0u) continue;
      if ((DEC[j >> 6] >> (j & 63)) & 1ull) continue;
      const uint* lj = list + ((size_t)b * ROWP + j) * KSUP;
      uint c = myCnt[r] < KSUP ? myCnt[r] : KSUP;
      bool anyAlive = false, pending = false;
      for (uint m = 0; m < c; ++m) {
        uint i = lj[m];
        bool ai = (ALIVE[i >> 6] >> (i & 63)) & 1ull;
        bool di = (DEC[i >> 6] >> (i & 63)) & 1ull;
        if (ai) { anyAlive = true; break; }
        if (!di) pending = true;
      }
      if (anyAlive)      { decJ[r] = j; decAlive[r] = false; }
      else if (!pending) { decJ[r] = j; decAlive[r] = true;  }
    }
    __syncthreads();
    bool any = false;
    #pragma unroll
    for (int r = 0; r < 6; ++r) {
      if (decJ[r] >= 0) {
        int j = decJ[r];
        if (decAlive[r]) atomicOr(&ALIVE[j >> 6], 1ull << (j & 63));
        atomicOr(&DEC[j >> 6], 1ull << (j & 63));
        any = true;
      }
    }
    if (any) atomicAdd(&changed, 1);
    __syncthreads();
    if (changed == 0) break;
  }

  __shared__ uint pre[NWRD + 1];
  if (tid == 0) {
    uint c = 0;
    for (int w = 0; w < NWRD; ++w) { pre[w] = c; c += (uint)__popcll(ALIVE[w]); }
    pre[NWRD] = c;
  }
  __syncthreads();
  for (int q = tid; q < POST; q += 1024) out[(size_t)b * POST + q] = 0.0f;
  for (int t = tid; t < POST * 4; t += 1024) out[(size_t)BB * POST + (size_t)b * POST * 4 + t] = 0.0f;
  __syncthreads();
  for (int j = tid; j < PRE; j += 1024) {
    int w = j >> 6, bit = j & 63;
    u64 word = ALIVE[w];
    if ((word >> bit) & 1ull) {
      uint rank = pre[w] + (uint)__popcll(word & ((1ull << bit) - 1ull));
      if (rank < POST) {
        out[(size_t)b * POST + rank] = score6k[(size_t)b * ROWP + j];
        float4 bx = boxes6k[(size_t)b * ROWP + j];
        float* o = out + (size_t)BB * POST + ((size_t)b * POST + rank) * 4;
        o[0] = bx.x; o[1] = bx.y; o[2] = bx.z; o[3] = bx.w;
      }
    }
  }
}

extern "C" void kernel_launch(void* const* d_in, const int* in_sizes, int n_in,
                              void* d_out, int out_size, void* d_ws, size_t ws_size,
                              hipStream_t stream) {
  const float4* props = (const float4*)d_in[0];
  const float2* clsp  = (const float2*)d_in[1];
  float* out = (float*)d_out;
  char* ws = (char*)d_ws;

  uint*   hdr     = (uint*)(ws + OFF_HDR);
  uint*   rtot    = (uint*)(ws + OFF_RTOT);
  uint*   bar     = (uint*)(ws + OFF_BAR);
  uint*   cnt     = (uint*)(ws + OFF_CNT);
  uint*   hist1   = (uint*)(ws + OFF_H1);
  uint*   base    = (uint*)(ws + OFF_BASE);
  uint*   keyhi   = (uint*)(ws + OFF_KEY);
  u64*    buck    = (u64*) (ws + OFF_BUCK);
  uint*   list    = (uint*)(ws + OFF_LIST);
  float4* boxes6k = (float4*)(ws + OFF_BOX);
  float*  score6k = (float*)(ws + OFF_SCO);
  float*  area6k  = (float*)(ws + OFF_AREA);
  u64*    validW  = (u64*) (ws + OFF_VAL);

  hipMemsetAsync(ws + OFF_BAR, 0, 64, stream);   // zero grid-barrier counters
  fused<<<NBLK, 256, 0, stream>>>(props, clsp, keyhi, hist1, base, hdr, rtot, bar,
                                  buck, boxes6k, score6k, area6k, validW, cnt, list);
  sparse_resolve<<<BB, 1024, 0, stream>>>(cnt, list, validW, score6k, boxes6k, out);
}

// Round 15
// 228.978 us; speedup vs baseline: 5.1904x; 5.1904x over previous
//
#include <hip/hip_runtime.h>
#include <hip/hip_bf16.h>
#include <math.h>

typedef unsigned int uint;
typedef unsigned long long u64;

#define BB 4
#define NN 100000
#define PRE 6000
#define POST 1000
#define NWRD 94          // 6000/64 rounded up
#define SCAP 8192        // bucketed capacity
#define ROWP 6016        // padded rows/cols
#define KSUP 64          // max suppressors tracked per box
#define NRANGE 32        // hist ranges per image (2048 bins each)
#define WQ 16            // col-words per sup_build block

// ---- workspace layout (bytes) ----
constexpr size_t OFF_HDR   = 0;                                    // 16 uints: t1[4], limit[4]
constexpr size_t OFF_RTOT  = 64;                                   // 128 uints: per-(b,range) totals
constexpr size_t OFF_CNT   = 1024;                                 // BB*ROWP*4 (zeroed by hist_range)
constexpr size_t OFF_H1    = OFF_CNT + (size_t)BB*ROWP*4;          // hist1: 1MB (fully overwritten)
constexpr size_t OFF_BASE  = OFF_H1  + (size_t)BB*65536*4;         // base:  1MB (fully overwritten)
constexpr size_t OFF_KEY   = OFF_BASE+ (size_t)BB*65536*4;         // keyhi: BB*NN*4
constexpr size_t OFF_BUCK  = OFF_KEY + (size_t)BB*NN*4;            // BB*SCAP*8
constexpr size_t OFF_LIST  = OFF_BUCK+ (size_t)BB*SCAP*8;          // BB*ROWP*KSUP*4
constexpr size_t OFF_BOX   = OFF_LIST+ (size_t)BB*ROWP*KSUP*4;
constexpr size_t OFF_SCO   = OFF_BOX + (size_t)BB*ROWP*16;
constexpr size_t OFF_AREA  = OFF_SCO + (size_t)BB*ROWP*4;
constexpr size_t OFF_VAL   = OFF_AREA+ (size_t)BB*ROWP*4;          // validW (zeroed by scan128)

__device__ __forceinline__ float clipf(float v, float hi) {
  return fminf(fmaxf(v, 0.0f), hi);
}

// ---------- pass 1a: keys only (pure streaming, no atomics) ----------
__global__ void keys_only(const float4* __restrict__ props,
                          const float2* __restrict__ clsp,
                          uint* __restrict__ keyhi) {
  int b = blockIdx.y;
  int i = blockIdx.x * 256 + threadIdx.x;
  if (i >= NN) return;
  float4 p = props[(size_t)b * NN + i];
  float x1 = clipf(p.x, 800.0f), y1 = clipf(p.y, 800.0f);
  float x2 = clipf(p.z, 800.0f), y2 = clipf(p.w, 800.0f);
  bool valid = ((x2 - x1) >= 16.0f) && ((y2 - y1) >= 16.0f);
  float s  = clsp[(size_t)b * NN + i].y;
  float sm = valid ? s : -INFINITY;
  uint u = __float_as_uint(sm);
  u = (u & 0x80000000u) ? ~u : (u | 0x80000000u);  // monotonic: ascending u == ascending score
  keyhi[(size_t)b * NN + i] = ~u;                   // ascending key == DESCENDING score
}

// ---------- pass 1b: range-partitioned LDS histogram -> hist1 + rtot ----------
// Block (r,b) owns bins [r*2048,(r+1)*2048). Tail zeroes its slice of cnt.
__global__ __launch_bounds__(256) void hist_range(const uint4* __restrict__ keyhi4,
                                                  uint* __restrict__ hist1,
                                                  uint* __restrict__ rtot,
                                                  uint* __restrict__ cnt) {
  int b = blockIdx.y;
  int r = blockIdx.x;
  uint lo = (uint)r << 11;     // 2048 bins per range block
  __shared__ uint lh[2048];
  __shared__ uint wr[4];
  int tid = threadIdx.x, lane = tid & 63, W = tid >> 6;
  for (int i = tid; i < 2048; i += 256) lh[i] = 0u;
  __syncthreads();
  const uint4* K = keyhi4 + (size_t)b * (NN / 4);
  for (int i = tid; i < NN / 4; i += 256) {
    uint4 v = K[i];
    uint b0 = (v.x >> 16) - lo; if (b0 < 2048u) atomicAdd(&lh[b0], 1u);
    uint b1 = (v.y >> 16) - lo; if (b1 < 2048u) atomicAdd(&lh[b1], 1u);
    uint b2 = (v.z >> 16) - lo; if (b2 < 2048u) atomicAdd(&lh[b2], 1u);
    uint b3 = (v.w >> 16) - lo; if (b3 < 2048u) atomicAdd(&lh[b3], 1u);
  }
  __syncthreads();
  uint* H = hist1 + (size_t)b * 65536 + lo;
  uint s = 0;
  for (int i = tid; i < 2048; i += 256) { H[i] = lh[i]; s += lh[i]; }
  for (int off = 32; off > 0; off >>= 1) s += __shfl_xor(s, off);
  if (lane == 0) wr[W] = s;
  __syncthreads();
  if (tid == 0) rtot[b * 32 + r] = wr[0] + wr[1] + wr[2] + wr[3];
  // zero this block's slice of cnt (ROWP = 32*188)
  uint* C = cnt + (size_t)b * ROWP + r * (ROWP / NRANGE);
  if (tid < ROWP / NRANGE) C[tid] = 0u;
}

// ---------- pass 2: per-range exclusive scan -> base[]; boundary -> hdr ----------
// 128 blocks (r,b); logic field-verified as phaseB2 in rounds 12-13.
__global__ __launch_bounds__(256) void scan128(const uint* __restrict__ hist1,
                                               const uint* __restrict__ rtot,
                                               uint* __restrict__ base,
                                               uint* __restrict__ hdr,
                                               u64* __restrict__ validW) {
  int r = blockIdx.x, b = blockIdx.y;
  int tid = threadIdx.x, lane = tid & 63, W = tid >> 6;
  __shared__ uint wt[4];
  if (r == 0 && tid < 96) validW[(size_t)b * 96 + tid] = 0ull;
  uint lo = (uint)r << 11;
  uint rbase = 0, tot = 0;
  for (int k = 0; k < 32; ++k) {
    uint v = rtot[b * 32 + k];
    if (k < r) rbase += v;
    if (k == r) tot = v;
  }
  const uint* h = hist1 + (size_t)b * 65536 + lo;
  uint c[8], s = 0;
  for (int k = 0; k < 8; ++k) { c[k] = h[tid * 8 + k]; s += c[k]; }
  uint ps = s;
  for (int off = 1; off < 64; off <<= 1) {
    uint v = __shfl_up(ps, off);
    if (lane >= off) ps += v;
  }
  if (lane == 63) wt[W] = ps;
  __syncthreads();
  uint wbase = 0;
  for (int k = 0; k < 4; ++k) { if (k < W) wbase += wt[k]; }
  uint excl = rbase + wbase + ps - s;     // global exclusive before thread's bins
  uint run = excl;
  uint* bs = base + (size_t)b * 65536 + lo;
  for (int k = 0; k < 8; ++k) { bs[tid * 8 + k] = run; run += c[k]; }
  // boundary bucket (cumulative position PRE); total over all ranges = NN > PRE
  if (rbase < (uint)PRE && (uint)PRE <= rbase + tot) {
    uint cc = excl;
    for (int k = 0; k < 8; ++k) {
      uint hv = c[k];
      if (cc < (uint)PRE && (uint)PRE <= cc + hv) {
        hdr[0 + b] = lo + (uint)(tid * 8 + k);   // t1 boundary bucket
        hdr[4 + b] = cc + hv;                    // limit = cumulative through t1
      }
      cc += hv;
    }
  }
}

// ---------- pass 3: scatter elems of buckets <= t1 into bucket slots ----------
__global__ void bucket_scatter(const uint* __restrict__ keyhi,
                               uint* __restrict__ base,
                               const uint* __restrict__ hdr,
                               u64* __restrict__ buck) {
  int b = blockIdx.y;
  int i = blockIdx.x * 256 + threadIdx.x;
  if (i >= NN) return;
  uint kh = keyhi[(size_t)b * NN + i];
  if ((kh >> 16) <= hdr[0 + b]) {
    uint pos = atomicAdd(&base[(size_t)b * 65536 + (kh >> 16)], 1u);
    if (pos < SCAP) buck[(size_t)b * SCAP + pos] = ((u64)kh << 32) | (uint)i;
  }
}

// ---------- pass 4: exact rank -> direct scatter of box/score/area/validW ----
__global__ void rank_scatter(const u64* __restrict__ buck,
                             const uint* __restrict__ base,
                             const uint* __restrict__ hist,
                             const uint* __restrict__ hdr,
                             const float4* __restrict__ props,
                             const float2* __restrict__ clsp,
                             float4* __restrict__ boxes6k,
                             float* __restrict__ score6k,
                             float* __restrict__ area6k,
                             u64* __restrict__ validW) {
  int b = blockIdx.y;
  int s = blockIdx.x * 256 + threadIdx.x;
  uint limit = hdr[4 + b];
  if (s >= (int)limit) return;
  u64 v = buck[(size_t)b * SCAP + s];
  uint bkt = (uint)(v >> 48);
  uint cntb = hist[(size_t)b * 65536 + bkt];
  uint b0 = base[(size_t)b * 65536 + bkt] - cntb;  // restore pre-scatter base
  uint r = b0;
  for (uint m = 0; m < cntb; ++m) {
    u64 w = buck[(size_t)b * SCAP + b0 + m];
    r += (w < v) ? 1u : 0u;                        // (key,idx) stable order
  }
  if (r >= (uint)PRE) return;
  uint idx = (uint)(v & 0xFFFFFFFFull);
  float4 p = props[(size_t)b * NN + idx];
  float x1 = clipf(p.x, 800.0f), y1 = clipf(p.y, 800.0f);
  float x2 = clipf(p.z, 800.0f), y2 = clipf(p.w, 800.0f);
  float w = x2 - x1, h = y2 - y1;
  bool valid = (w >= 16.0f) && (h >= 16.0f);
  float4 bx; bx.x = x1; bx.y = y1; bx.z = x2; bx.w = y2;
  boxes6k[(size_t)b * ROWP + r] = bx;
  score6k[(size_t)b * ROWP + r] = clsp[(size_t)b * NN + idx].y;
  area6k [(size_t)b * ROWP + r] = fmaxf(w, 0.0f) * fmaxf(h, 0.0f);
  if (valid) atomicOr(&validW[(size_t)b * 96 + (r >> 6)], 1ull << (r & 63));
}

// ---------- pass 5: sparse suppressor-list build ----------
// Hot loop is pure f32 with an exact guard band; borderline pairs (rare)
// are fixed up with the exact f64 midpoint test afterwards.
// Exactness: keep <=> (double)inter >= M*(double)un, M = 0.7f + 2^-25 =
// 0x1.6666668p-1 (rounding midpoint; tie rounds-to-even UP; 25b x 24b = 49
// bits <= 53, conversions exact). f32 shortcut: with inter <= un,
// d = fl(fl(inter - 0.7f*un) - un*2^-25) satisfies |d - Q| <= 2^-23*un where
// Q = inter - M*un, so |d| > un*2^-21 decides sign(Q) exactly.
__global__ __launch_bounds__(256) void sup_build(const float4* __restrict__ boxes6k,
                                                 const float* __restrict__ area6k,
                                                 const u64* __restrict__ validW,
                                                 uint* __restrict__ cnt,
                                                 uint* __restrict__ list) {
  int gb = blockIdx.y, b = blockIdx.z;
  int cw0 = blockIdx.x * WQ;
  if (cw0 + WQ - 1 < gb) return;       // block fully below the diagonal
  int w = threadIdx.x >> 6, lane = threadIdx.x & 63;
  __shared__ float4 rbox[64];
  __shared__ float  rar[64];
  if (threadIdx.x < 64) {
    rbox[lane] = boxes6k[(size_t)b * ROWP + gb * 64 + lane];
    rar[lane]  = area6k [(size_t)b * ROWP + gb * 64 + lane];
  }
  __syncthreads();
  u64 vmask = validW[(size_t)b * 96 + gb];

  int    cw[4];
  u64    rowsel[4], bits[4], bord[4];
  float4 cbox[4];
  float  carea[4];
  #pragma unroll
  for (int k = 0; k < 4; ++k) {
    cw[k] = cw0 + 4 * k + w;            // wave w owns words cw0+w, +4, +8, +12
    int col = cw[k] * 64 + lane;
    int colc = col < (ROWP - 1) ? col : (ROWP - 1);
    cbox[k]  = boxes6k[(size_t)b * ROWP + colc];
    carea[k] = area6k [(size_t)b * ROWP + colc];
    rowsel[k] = (cw[k] > gb) ? vmask
              : ((cw[k] == gb && lane) ? (vmask & ((1ull << lane) - 1ull)) : 0ull);
    bits[k] = 0ull; bord[k] = 0ull;
  }

  #pragma unroll 4
  for (int r = 0; r < 64; ++r) {
    float4 rb = rbox[r];
    float  ra = rar[r];
    u64 m = 1ull << r;
    #pragma unroll
    for (int k = 0; k < 4; ++k) {
      float xx1 = fmaxf(rb.x, cbox[k].x), yy1 = fmaxf(rb.y, cbox[k].y);
      float xx2 = fminf(rb.z, cbox[k].z), yy2 = fminf(rb.w, cbox[k].w);
      float inter = fmaxf(xx2 - xx1, 0.0f) * fmaxf(yy2 - yy1, 0.0f);
      float un = fmaxf(ra + carea[k] - inter, 1e-9f);
      float d  = fmaf(-0.7f, un, inter) - un * 0x1p-25f;
      bits[k] |= (d > 0.0f) ? m : 0ull;
      bord[k] |= (fabsf(d) <= un * 0x1p-21f) ? m : 0ull;
    }
  }

  const double M = 0x1.6666668p-1;
  int rbase = gb * 64;
  #pragma unroll
  for (int k = 0; k < 4; ++k) {
    if (cw[k] >= NWRD) continue;
    // exact fix-up of borderline bits (rare)
    u64 bd = bord[k] & rowsel[k];
    while (bd) {
      int r = __ffsll((long long)bd) - 1;
      bd &= bd - 1;
      float4 rb = rbox[r];
      float xx1 = fmaxf(rb.x, cbox[k].x), yy1 = fmaxf(rb.y, cbox[k].y);
      float xx2 = fminf(rb.z, cbox[k].z), yy2 = fminf(rb.w, cbox[k].w);
      float inter = fmaxf(xx2 - xx1, 0.0f) * fmaxf(yy2 - yy1, 0.0f);
      float un = fmaxf(rar[r] + carea[k] - inter, 1e-9f);
      if ((double)inter >= M * (double)un) bits[k] |= 1ull << r;
      else                                 bits[k] &= ~(1ull << r);
    }
    u64 bt = bits[k] & rowsel[k];
    int col = cw[k] * 64 + lane;
    while (bt) {
      int r = __ffsll((long long)bt) - 1;
      bt &= bt - 1;
      uint pos = atomicAdd(&cnt[(size_t)b * ROWP + col], 1u);
      if (pos < KSUP) list[((size_t)b * ROWP + col) * KSUP + pos] = (uint)(rbase + r);
    }
  }
}

// ---------- pass 6: sparse Jacobi fixpoint resolve + fused finalize ----------
__global__ __launch_bounds__(1024) void sparse_resolve(const uint* __restrict__ cnt,
                                                       const uint* __restrict__ list,
                                                       const u64* __restrict__ validW,
                                                       const float* __restrict__ score6k,
                                                       const float4* __restrict__ boxes6k,
                                                       float* __restrict__ out) {
  int b = blockIdx.x, tid = threadIdx.x;
  __shared__ u64 ALIVE[96], DEC[96], VW[96];
  __shared__ int changed;
  if (tid < 96) {
    ALIVE[tid] = 0ull; DEC[tid] = 0ull;
    VW[tid] = validW[(size_t)b * 96 + tid];
  }
  __syncthreads();

  uint myCnt[6];
  #pragma unroll
  for (int r = 0; r < 6; ++r) {
    int j = tid + r * 1024;
    myCnt[r] = (j < PRE) ? cnt[(size_t)b * ROWP + j] : 0u;
  }
  #pragma unroll
  for (int r = 0; r < 6; ++r) {
    int j = tid + r * 1024;
    if (j >= PRE) continue;
    bool valid = (VW[j >> 6] >> (j & 63)) & 1ull;
    if (myCnt[r] == 0u || !valid) {
      atomicOr(&DEC[j >> 6], 1ull << (j & 63));
      if (valid) atomicOr(&ALIVE[j >> 6], 1ull << (j & 63));
    }
  }
  __syncthreads();

  while (true) {
    if (tid == 0) changed = 0;
    __syncthreads();
    int decJ[6]; bool decAlive[6];
    #pragma unroll
    for (int r = 0; r < 6; ++r) {
      decJ[r] = -1; decAlive[r] = false;
      int j = tid + r * 1024;
      if (j >= PRE || myCnt[r] == 0u) continue;
      if ((DEC[j >> 6] >> (j & 63)) & 1ull) continue;
      const uint* lj = list + ((size_t)b * ROWP + j) * KSUP;
      uint c = myCnt[r] < KSUP ? myCnt[r] : KSUP;
      bool anyAlive = false, pending = false;
      for (uint m = 0; m < c; ++m) {
        uint i = lj[m];
        bool ai = (ALIVE[i >> 6] >> (i & 63)) & 1ull;
        bool di = (DEC[i >> 6] >> (i & 63)) & 1ull;
        if (ai) { anyAlive = true; break; }
        if (!di) pending = true;
      }
      if (anyAlive)      { decJ[r] = j; decAlive[r] = false; }
      else if (!pending) { decJ[r] = j; decAlive[r] = true;  }
    }
    __syncthreads();
    bool any = false;
    #pragma unroll
    for (int r = 0; r < 6; ++r) {
      if (decJ[r] >= 0) {
        int j = decJ[r];
        if (decAlive[r]) atomicOr(&ALIVE[j >> 6], 1ull << (j & 63));
        atomicOr(&DEC[j >> 6], 1ull << (j & 63));
        any = true;
      }
    }
    if (any) atomicAdd(&changed, 1);
    __syncthreads();
    if (changed == 0) break;
  }

  __shared__ uint pre[NWRD + 1];
  if (tid == 0) {
    uint c = 0;
    for (int w = 0; w < NWRD; ++w) { pre[w] = c; c += (uint)__popcll(ALIVE[w]); }
    pre[NWRD] = c;
  }
  __syncthreads();
  for (int q = tid; q < POST; q += 1024) out[(size_t)b * POST + q] = 0.0f;
  for (int t = tid; t < POST * 4; t += 1024) out[(size_t)BB * POST + (size_t)b * POST * 4 + t] = 0.0f;
  __syncthreads();
  for (int j = tid; j < PRE; j += 1024) {
    int w = j >> 6, bit = j & 63;
    u64 word = ALIVE[w];
    if ((word >> bit) & 1ull) {
      uint rank = pre[w] + (uint)__popcll(word & ((1ull << bit) - 1ull));
      if (rank < POST) {
        out[(size_t)b * POST + rank] = score6k[(size_t)b * ROWP + j];
        float4 bx = boxes6k[(size_t)b * ROWP + j];
        float* o = out + (size_t)BB * POST + ((size_t)b * POST + rank) * 4;
        o[0] = bx.x; o[1] = bx.y; o[2] = bx.z; o[3] = bx.w;
      }
    }
  }
}

extern "C" void kernel_launch(void* const* d_in, const int* in_sizes, int n_in,
                              void* d_out, int out_size, void* d_ws, size_t ws_size,
                              hipStream_t stream) {
  const float4* props = (const float4*)d_in[0];
  const float2* clsp  = (const float2*)d_in[1];
  float* out = (float*)d_out;
  char* ws = (char*)d_ws;

  uint*   hdr     = (uint*)(ws + OFF_HDR);
  uint*   rtot    = (uint*)(ws + OFF_RTOT);
  uint*   cnt     = (uint*)(ws + OFF_CNT);
  uint*   hist1   = (uint*)(ws + OFF_H1);
  uint*   base    = (uint*)(ws + OFF_BASE);
  uint*   keyhi   = (uint*)(ws + OFF_KEY);
  u64*    buck    = (u64*) (ws + OFF_BUCK);
  uint*   list    = (uint*)(ws + OFF_LIST);
  float4* boxes6k = (float4*)(ws + OFF_BOX);
  float*  score6k = (float*)(ws + OFF_SCO);
  float*  area6k  = (float*)(ws + OFF_AREA);
  u64*    validW  = (u64*) (ws + OFF_VAL);

  dim3 gN((NN + 255) / 256, BB);
  keys_only<<<gN, 256, 0, stream>>>(props, clsp, keyhi);
  hist_range<<<dim3(NRANGE, BB), 256, 0, stream>>>((const uint4*)keyhi, hist1, rtot, cnt);
  scan128<<<dim3(NRANGE, BB), 256, 0, stream>>>(hist1, rtot, base, hdr, validW);
  bucket_scatter<<<gN, 256, 0, stream>>>(keyhi, base, hdr, buck);
  rank_scatter<<<dim3(SCAP / 256, BB), 256, 0, stream>>>(buck, base, hist1, hdr,
                                                         props, clsp, boxes6k,
                                                         score6k, area6k, validW);
  sup_build<<<dim3((NWRD + WQ - 1) / WQ, NWRD, BB), 256, 0, stream>>>(boxes6k, area6k,
                                                                      validW, cnt, list);
  sparse_resolve<<<BB, 1024, 0, stream>>>(cnt, list, validW, score6k, boxes6k, out);
}

// Round 16
// 160.903 us; speedup vs baseline: 7.3864x; 1.4231x over previous
//
#include <hip/hip_runtime.h>
#include <hip/hip_bf16.h>
#include <math.h>

typedef unsigned int uint;
typedef unsigned long long u64;

#define BB 4
#define NN 100000
#define PRE 6000
#define POST 1000
#define NWRD 94          // 6000/64 rounded up
#define PREF 2048        // NMS prefix (exact if >=1000 kept inside; else fallback)
#define PWRD 32          // PREF/64
#define SCAP 8192        // bucketed capacity
#define ROWP 6016        // padded rows/cols
#define KSUP 64          // max suppressors tracked per box
#define NRANGE 32        // hist ranges per image (2048 bins each)
#define WQ 16            // col-words per sup_build block

// ---- workspace layout (bytes) ----
constexpr size_t OFF_HDR   = 0;                                    // uints: t1[4], limit[4], done[4]
constexpr size_t OFF_RTOT  = 64;                                   // 128 uints: per-(b,range) totals
constexpr size_t OFF_CNT   = 1024;                                 // BB*ROWP*4 (zeroed by hist_range)
constexpr size_t OFF_H1    = OFF_CNT + (size_t)BB*ROWP*4;          // hist1: 1MB (fully overwritten)
constexpr size_t OFF_BASE  = OFF_H1  + (size_t)BB*65536*4;         // base:  1MB (fully overwritten)
constexpr size_t OFF_KEY   = OFF_BASE+ (size_t)BB*65536*4;         // keyhi: BB*NN*4
constexpr size_t OFF_BUCK  = OFF_KEY + (size_t)BB*NN*4;            // BB*SCAP*8
constexpr size_t OFF_LIST  = OFF_BUCK+ (size_t)BB*SCAP*8;          // BB*ROWP*KSUP*4
constexpr size_t OFF_BOX   = OFF_LIST+ (size_t)BB*ROWP*KSUP*4;
constexpr size_t OFF_SCO   = OFF_BOX + (size_t)BB*ROWP*16;
constexpr size_t OFF_AREA  = OFF_SCO + (size_t)BB*ROWP*4;
constexpr size_t OFF_VAL   = OFF_AREA+ (size_t)BB*ROWP*4;          // validW (zeroed by scan128)

__device__ __forceinline__ float clipf(float v, float hi) {
  return fminf(fmaxf(v, 0.0f), hi);
}

// ---------- pass 1a: keys only (pure streaming, no atomics) ----------
__global__ void keys_only(const float4* __restrict__ props,
                          const float2* __restrict__ clsp,
                          uint* __restrict__ keyhi) {
  int b = blockIdx.y;
  int i = blockIdx.x * 256 + threadIdx.x;
  if (i >= NN) return;
  float4 p = props[(size_t)b * NN + i];
  float x1 = clipf(p.x, 800.0f), y1 = clipf(p.y, 800.0f);
  float x2 = clipf(p.z, 800.0f), y2 = clipf(p.w, 800.0f);
  bool valid = ((x2 - x1) >= 16.0f) && ((y2 - y1) >= 16.0f);
  float s  = clsp[(size_t)b * NN + i].y;
  float sm = valid ? s : -INFINITY;
  uint u = __float_as_uint(sm);
  u = (u & 0x80000000u) ? ~u : (u | 0x80000000u);  // monotonic: ascending u == ascending score
  keyhi[(size_t)b * NN + i] = ~u;                   // ascending key == DESCENDING score
}

// ---------- pass 1b: range-partitioned LDS histogram -> hist1 + rtot ----------
__global__ __launch_bounds__(256) void hist_range(const uint4* __restrict__ keyhi4,
                                                  uint* __restrict__ hist1,
                                                  uint* __restrict__ rtot,
                                                  uint* __restrict__ cnt) {
  int b = blockIdx.y;
  int r = blockIdx.x;
  uint lo = (uint)r << 11;     // 2048 bins per range block
  __shared__ uint lh[2048];
  __shared__ uint wr[4];
  int tid = threadIdx.x, lane = tid & 63, W = tid >> 6;
  for (int i = tid; i < 2048; i += 256) lh[i] = 0u;
  __syncthreads();
  const uint4* K = keyhi4 + (size_t)b * (NN / 4);
  for (int i = tid; i < NN / 4; i += 256) {
    uint4 v = K[i];
    uint b0 = (v.x >> 16) - lo; if (b0 < 2048u) atomicAdd(&lh[b0], 1u);
    uint b1 = (v.y >> 16) - lo; if (b1 < 2048u) atomicAdd(&lh[b1], 1u);
    uint b2 = (v.z >> 16) - lo; if (b2 < 2048u) atomicAdd(&lh[b2], 1u);
    uint b3 = (v.w >> 16) - lo; if (b3 < 2048u) atomicAdd(&lh[b3], 1u);
  }
  __syncthreads();
  uint* H = hist1 + (size_t)b * 65536 + lo;
  uint s = 0;
  for (int i = tid; i < 2048; i += 256) { H[i] = lh[i]; s += lh[i]; }
  for (int off = 32; off > 0; off >>= 1) s += __shfl_xor(s, off);
  if (lane == 0) wr[W] = s;
  __syncthreads();
  if (tid == 0) rtot[b * 32 + r] = wr[0] + wr[1] + wr[2] + wr[3];
  uint* C = cnt + (size_t)b * ROWP + r * (ROWP / NRANGE);
  if (tid < ROWP / NRANGE) C[tid] = 0u;
}

// ---------- pass 2: per-range exclusive scan -> base[]; boundary -> hdr ----------
__global__ __launch_bounds__(256) void scan128(const uint* __restrict__ hist1,
                                               const uint* __restrict__ rtot,
                                               uint* __restrict__ base,
                                               uint* __restrict__ hdr,
                                               u64* __restrict__ validW) {
  int r = blockIdx.x, b = blockIdx.y;
  int tid = threadIdx.x, lane = tid & 63, W = tid >> 6;
  __shared__ uint wt[4];
  if (r == 0 && tid < 96) validW[(size_t)b * 96 + tid] = 0ull;
  uint lo = (uint)r << 11;
  uint rbase = 0, tot = 0;
  for (int k = 0; k < 32; ++k) {
    uint v = rtot[b * 32 + k];
    if (k < r) rbase += v;
    if (k == r) tot = v;
  }
  const uint* h = hist1 + (size_t)b * 65536 + lo;
  uint c[8], s = 0;
  for (int k = 0; k < 8; ++k) { c[k] = h[tid * 8 + k]; s += c[k]; }
  uint ps = s;
  for (int off = 1; off < 64; off <<= 1) {
    uint v = __shfl_up(ps, off);
    if (lane >= off) ps += v;
  }
  if (lane == 63) wt[W] = ps;
  __syncthreads();
  uint wbase = 0;
  for (int k = 0; k < 4; ++k) { if (k < W) wbase += wt[k]; }
  uint excl = rbase + wbase + ps - s;     // global exclusive before thread's bins
  uint run = excl;
  uint* bs = base + (size_t)b * 65536 + lo;
  for (int k = 0; k < 8; ++k) { bs[tid * 8 + k] = run; run += c[k]; }
  if (rbase < (uint)PRE && (uint)PRE <= rbase + tot) {
    uint cc = excl;
    for (int k = 0; k < 8; ++k) {
      uint hv = c[k];
      if (cc < (uint)PRE && (uint)PRE <= cc + hv) {
        hdr[0 + b] = lo + (uint)(tid * 8 + k);   // t1 boundary bucket
        hdr[4 + b] = cc + hv;                    // limit = cumulative through t1
      }
      cc += hv;
    }
  }
}

// ---------- pass 3: scatter elems of buckets <= t1 into bucket slots ----------
__global__ void bucket_scatter(const uint* __restrict__ keyhi,
                               uint* __restrict__ base,
                               const uint* __restrict__ hdr,
                               u64* __restrict__ buck) {
  int b = blockIdx.y;
  int i = blockIdx.x * 256 + threadIdx.x;
  if (i >= NN) return;
  uint kh = keyhi[(size_t)b * NN + i];
  if ((kh >> 16) <= hdr[0 + b]) {
    uint pos = atomicAdd(&base[(size_t)b * 65536 + (kh >> 16)], 1u);
    if (pos < SCAP) buck[(size_t)b * SCAP + pos] = ((u64)kh << 32) | (uint)i;
  }
}

// ---------- pass 4: exact rank -> direct scatter of box/score/area/validW ----
__global__ void rank_scatter(const u64* __restrict__ buck,
                             const uint* __restrict__ base,
                             const uint* __restrict__ hist,
                             const uint* __restrict__ hdr,
                             const float4* __restrict__ props,
                             const float2* __restrict__ clsp,
                             float4* __restrict__ boxes6k,
                             float* __restrict__ score6k,
                             float* __restrict__ area6k,
                             u64* __restrict__ validW) {
  int b = blockIdx.y;
  int s = blockIdx.x * 256 + threadIdx.x;
  uint limit = hdr[4 + b];
  if (s >= (int)limit) return;
  u64 v = buck[(size_t)b * SCAP + s];
  uint bkt = (uint)(v >> 48);
  uint cntb = hist[(size_t)b * 65536 + bkt];
  uint b0 = base[(size_t)b * 65536 + bkt] - cntb;  // restore pre-scatter base
  uint r = b0;
  for (uint m = 0; m < cntb; ++m) {
    u64 w = buck[(size_t)b * SCAP + b0 + m];
    r += (w < v) ? 1u : 0u;                        // (key,idx) stable order
  }
  if (r >= (uint)PRE) return;
  uint idx = (uint)(v & 0xFFFFFFFFull);
  float4 p = props[(size_t)b * NN + idx];
  float x1 = clipf(p.x, 800.0f), y1 = clipf(p.y, 800.0f);
  float x2 = clipf(p.z, 800.0f), y2 = clipf(p.w, 800.0f);
  float w = x2 - x1, h = y2 - y1;
  bool valid = (w >= 16.0f) && (h >= 16.0f);
  float4 bx; bx.x = x1; bx.y = y1; bx.z = x2; bx.w = y2;
  boxes6k[(size_t)b * ROWP + r] = bx;
  score6k[(size_t)b * ROWP + r] = clsp[(size_t)b * NN + idx].y;
  area6k [(size_t)b * ROWP + r] = fmaxf(w, 0.0f) * fmaxf(h, 0.0f);
  if (valid) atomicOr(&validW[(size_t)b * 96 + (r >> 6)], 1ull << (r & 63));
}

// ---------- shared sup tile body (exact division-free IoU test) ----------
// fl32(inter/un) > 0.7f  <=>  (double)inter >= M*(double)un,
// M = 0.7f + 2^-25 = 0x1.6666668p-1 (rounding midpoint; the tie
// rounds-to-even UP; 25b x 24b = 49 bits <= 53, conversions exact, un>0).
__device__ __forceinline__
void sup_tile(int b, int gb, int cw0, int wmax,
              const float4* boxes6k, const float* area6k, const u64* validW,
              uint* cnt, uint* list,
              float4* rbox, float* rar /* LDS, filled here */) {
  int w = threadIdx.x >> 6, lane = threadIdx.x & 63;
  if (threadIdx.x < 64) {
    rbox[lane] = boxes6k[(size_t)b * ROWP + gb * 64 + lane];
    rar[lane]  = area6k [(size_t)b * ROWP + gb * 64 + lane];
  }
  __syncthreads();
  u64 vmask = validW[(size_t)b * 96 + gb];

  int    cw[4];
  u64    rowsel[4], bits[4];
  float4 cbox[4];
  float  carea[4];
  #pragma unroll
  for (int k = 0; k < 4; ++k) {
    cw[k] = cw0 + 4 * k + w;            // wave w owns words cw0+w, +4, +8, +12
    int col = cw[k] * 64 + lane;
    int colc = col < (ROWP - 1) ? col : (ROWP - 1);
    cbox[k]  = boxes6k[(size_t)b * ROWP + colc];
    carea[k] = area6k [(size_t)b * ROWP + colc];
    rowsel[k] = (cw[k] > gb) ? vmask
              : ((cw[k] == gb && lane) ? (vmask & ((1ull << lane) - 1ull)) : 0ull);
    bits[k] = 0ull;
  }

  const double M = 0x1.6666668p-1;      // exact decision midpoint for (iou > 0.7f)
  #pragma unroll 4
  for (int r = 0; r < 64; ++r) {
    float4 rb = rbox[r];
    float  ra = rar[r];
    u64 m = 1ull << r;
    #pragma unroll
    for (int k = 0; k < 4; ++k) {
      float xx1 = fmaxf(rb.x, cbox[k].x), yy1 = fmaxf(rb.y, cbox[k].y);
      float xx2 = fminf(rb.z, cbox[k].z), yy2 = fminf(rb.w, cbox[k].w);
      float inter = fmaxf(xx2 - xx1, 0.0f) * fmaxf(yy2 - yy1, 0.0f);
      float un = fmaxf(ra + carea[k] - inter, 1e-9f);
      bits[k] |= ((double)inter >= M * (double)un) ? m : 0ull;
    }
  }

  int rbase = gb * 64;
  #pragma unroll
  for (int k = 0; k < 4; ++k) {
    if (cw[k] >= wmax) continue;
    u64 bt = bits[k] & rowsel[k];
    int col = cw[k] * 64 + lane;
    while (bt) {
      int r = __ffsll((long long)bt) - 1;
      bt &= bt - 1;
      uint pos = atomicAdd(&cnt[(size_t)b * ROWP + col], 1u);
      if (pos < KSUP) list[((size_t)b * ROWP + col) * KSUP + pos] = (uint)(rbase + r);
    }
  }
}

// ---------- pass 5a: suppressor lists within prefix [0, PREF) ----------
__global__ __launch_bounds__(256) void sup_build_pre(const float4* __restrict__ boxes6k,
                                                     const float* __restrict__ area6k,
                                                     const u64* __restrict__ validW,
                                                     uint* __restrict__ cnt,
                                                     uint* __restrict__ list) {
  int gb = blockIdx.y, b = blockIdx.z;
  int cw0 = blockIdx.x * WQ;            // 0 or 16
  if (cw0 + WQ - 1 < gb) return;        // fully below diagonal
  __shared__ float4 rbox[64];
  __shared__ float  rar[64];
  sup_tile(b, gb, cw0, PWRD, boxes6k, area6k, validW, cnt, list, rbox, rar);
}

// ---------- pass 5b: fallback — remaining tiles, only if !done[b] ----------
__global__ __launch_bounds__(256) void sup_build_full(const float4* __restrict__ boxes6k,
                                                      const float* __restrict__ area6k,
                                                      const u64* __restrict__ validW,
                                                      const uint* __restrict__ hdr,
                                                      uint* __restrict__ cnt,
                                                      uint* __restrict__ list) {
  int gb = blockIdx.y, b = blockIdx.z;
  if (hdr[8 + b]) return;               // prefix sufficed for this image
  int cw0 = blockIdx.x * WQ;
  if (cw0 + WQ - 1 < gb) return;        // fully below diagonal
  if (gb < PWRD && cw0 + WQ <= PWRD) return;  // prefix tiles already built
  __shared__ float4 rbox[64];
  __shared__ float  rar[64];
  sup_tile(b, gb, cw0, NWRD, boxes6k, area6k, validW, cnt, list, rbox, rar);
}

// ---------- pass 6a: prefix resolve + finalize; sets done[b] ----------
__global__ __launch_bounds__(1024) void resolve_pre(const uint* __restrict__ cnt,
                                                    const uint* __restrict__ list,
                                                    const u64* __restrict__ validW,
                                                    const float* __restrict__ score6k,
                                                    const float4* __restrict__ boxes6k,
                                                    uint* __restrict__ hdr,
                                                    float* __restrict__ out) {
  int b = blockIdx.x, tid = threadIdx.x;
  __shared__ u64 ALIVE[PWRD], DEC[PWRD], VW[PWRD];
  __shared__ int changed;
  if (tid < PWRD) {
    ALIVE[tid] = 0ull; DEC[tid] = 0ull;
    VW[tid] = validW[(size_t)b * 96 + tid];
  }
  __syncthreads();

  uint myCnt[2];
  #pragma unroll
  for (int r = 0; r < 2; ++r) {
    int j = tid + r * 1024;
    myCnt[r] = (j < PREF) ? cnt[(size_t)b * ROWP + j] : 0u;
  }
  #pragma unroll
  for (int r = 0; r < 2; ++r) {
    int j = tid + r * 1024;
    if (j >= PREF) continue;
    bool valid = (VW[j >> 6] >> (j & 63)) & 1ull;
    if (myCnt[r] == 0u || !valid) {
      atomicOr(&DEC[j >> 6], 1ull << (j & 63));
      if (valid) atomicOr(&ALIVE[j >> 6], 1ull << (j & 63));
    }
  }
  __syncthreads();

  while (true) {
    if (tid == 0) changed = 0;
    __syncthreads();
    int decJ[2]; bool decAlive[2];
    #pragma unroll
    for (int r = 0; r < 2; ++r) {
      decJ[r] = -1; decAlive[r] = false;
      int j = tid + r * 1024;
      if (j >= PREF || myCnt[r] == 0u) continue;
      if ((DEC[j >> 6] >> (j & 63)) & 1ull) continue;
      const uint* lj = list + ((size_t)b * ROWP + j) * KSUP;
      uint c = myCnt[r] < KSUP ? myCnt[r] : KSUP;
      bool anyAlive = false, pending = false;
      for (uint m = 0; m < c; ++m) {
        uint i = lj[m];
        bool ai = (ALIVE[i >> 6] >> (i & 63)) & 1ull;
        bool di = (DEC[i >> 6] >> (i & 63)) & 1ull;
        if (ai) { anyAlive = true; break; }
        if (!di) pending = true;
      }
      if (anyAlive)      { decJ[r] = j; decAlive[r] = false; }
      else if (!pending) { decJ[r] = j; decAlive[r] = true;  }
    }
    __syncthreads();
    bool any = false;
    #pragma unroll
    for (int r = 0; r < 2; ++r) {
      if (decJ[r] >= 0) {
        int j = decJ[r];
        if (decAlive[r]) atomicOr(&ALIVE[j >> 6], 1ull << (j & 63));
        atomicOr(&DEC[j >> 6], 1ull << (j & 63));
        any = true;
      }
    }
    if (any) atomicAdd(&changed, 1);
    __syncthreads();
    if (changed == 0) break;
  }

  __shared__ uint psum[PWRD + 1];
  if (tid == 0) {
    uint c = 0;
    for (int w = 0; w < PWRD; ++w) { psum[w] = c; c += (uint)__popcll(ALIVE[w]); }
    psum[PWRD] = c;
    hdr[8 + b] = (c >= (uint)POST) ? 1u : 0u;
  }
  __syncthreads();
  if (psum[PWRD] < (uint)POST) return;   // fallback path will produce output

  for (int q = tid; q < POST; q += 1024) out[(size_t)b * POST + q] = 0.0f;
  for (int t = tid; t < POST * 4; t += 1024) out[(size_t)BB * POST + (size_t)b * POST * 4 + t] = 0.0f;
  __syncthreads();
  for (int j = tid; j < PREF; j += 1024) {
    int w = j >> 6, bit = j & 63;
    u64 word = ALIVE[w];
    if ((word >> bit) & 1ull) {
      uint rank = psum[w] + (uint)__popcll(word & ((1ull << bit) - 1ull));
      if (rank < POST) {
        out[(size_t)b * POST + rank] = score6k[(size_t)b * ROWP + j];
        float4 bx = boxes6k[(size_t)b * ROWP + j];
        float* o = out + (size_t)BB * POST + ((size_t)b * POST + rank) * 4;
        o[0] = bx.x; o[1] = bx.y; o[2] = bx.z; o[3] = bx.w;
      }
    }
  }
}

// ---------- pass 6b: full resolve + finalize (only if !done[b]) ----------
__global__ __launch_bounds__(1024) void resolve_full(const uint* __restrict__ cnt,
                                                     const uint* __restrict__ list,
                                                     const u64* __restrict__ validW,
                                                     const float* __restrict__ score6k,
                                                     const float4* __restrict__ boxes6k,
                                                     const uint* __restrict__ hdr,
                                                     float* __restrict__ out) {
  int b = blockIdx.x, tid = threadIdx.x;
  if (hdr[8 + b]) return;               // prefix path already produced output
  __shared__ u64 ALIVE[96], DEC[96], VW[96];
  __shared__ int changed;
  if (tid < 96) {
    ALIVE[tid] = 0ull; DEC[tid] = 0ull;
    VW[tid] = validW[(size_t)b * 96 + tid];
  }
  __syncthreads();

  uint myCnt[6];
  #pragma unroll
  for (int r = 0; r < 6; ++r) {
    int j = tid + r * 1024;
    myCnt[r] = (j < PRE) ? cnt[(size_t)b * ROWP + j] : 0u;
  }
  #pragma unroll
  for (int r = 0; r < 6; ++r) {
    int j = tid + r * 1024;
    if (j >= PRE) continue;
    bool valid = (VW[j >> 6] >> (j & 63)) & 1ull;
    if (myCnt[r] == 0u || !valid) {
      atomicOr(&DEC[j >> 6], 1ull << (j & 63));
      if (valid) atomicOr(&ALIVE[j >> 6], 1ull << (j & 63));
    }
  }
  __syncthreads();

  while (true) {
    if (tid == 0) changed = 0;
    __syncthreads();
    int decJ[6]; bool decAlive[6];
    #pragma unroll
    for (int r = 0; r < 6; ++r) {
      decJ[r] = -1; decAlive[r] = false;
      int j = tid + r * 1024;
      if (j >= PRE || myCnt[r] == 0u) continue;
      if ((DEC[j >> 6] >> (j & 63)) & 1ull) continue;
      const uint* lj = list + ((size_t)b * ROWP + j) * KSUP;
      uint c = myCnt[r] < KSUP ? myCnt[r] : KSUP;
      bool anyAlive = false, pending = false;
      for (uint m = 0; m < c; ++m) {
        uint i = lj[m];
        bool ai = (ALIVE[i >> 6] >> (i & 63)) & 1ull;
        bool di = (DEC[i >> 6] >> (i & 63)) & 1ull;
        if (ai) { anyAlive = true; break; }
        if (!di) pending = true;
      }
      if (anyAlive)      { decJ[r] = j; decAlive[r] = false; }
      else if (!pending) { decJ[r] = j; decAlive[r] = true;  }
    }
    __syncthreads();
    bool any = false;
    #pragma unroll
    for (int r = 0; r < 6; ++r) {
      if (decJ[r] >= 0) {
        int j = decJ[r];
        if (decAlive[r]) atomicOr(&ALIVE[j >> 6], 1ull << (j & 63));
        atomicOr(&DEC[j >> 6], 1ull << (j & 63));
        any = true;
      }
    }
    if (any) atomicAdd(&changed, 1);
    __syncthreads();
    if (changed == 0) break;
  }

  __shared__ uint psum[NWRD + 1];
  if (tid == 0) {
    uint c = 0;
    for (int w = 0; w < NWRD; ++w) { psum[w] = c; c += (uint)__popcll(ALIVE[w]); }
    psum[NWRD] = c;
  }
  __syncthreads();
  for (int q = tid; q < POST; q += 1024) out[(size_t)b * POST + q] = 0.0f;
  for (int t = tid; t < POST * 4; t += 1024) out[(size_t)BB * POST + (size_t)b * POST * 4 + t] = 0.0f;
  __syncthreads();
  for (int j = tid; j < PRE; j += 1024) {
    int w = j >> 6, bit = j & 63;
    u64 word = ALIVE[w];
    if ((word >> bit) & 1ull) {
      uint rank = psum[w] + (uint)__popcll(word & ((1ull << bit) - 1ull));
      if (rank < POST) {
        out[(size_t)b * POST + rank] = score6k[(size_t)b * ROWP + j];
        float4 bx = boxes6k[(size_t)b * ROWP + j];
        float* o = out + (size_t)BB * POST + ((size_t)b * POST + rank) * 4;
        o[0] = bx.x; o[1] = bx.y; o[2] = bx.z; o[3] = bx.w;
      }
    }
  }
}

extern "C" void kernel_launch(void* const* d_in, const int* in_sizes, int n_in,
                              void* d_out, int out_size, void* d_ws, size_t ws_size,
                              hipStream_t stream) {
  const float4* props = (const float4*)d_in[0];
  const float2* clsp  = (const float2*)d_in[1];
  float* out = (float*)d_out;
  char* ws = (char*)d_ws;

  uint*   hdr     = (uint*)(ws + OFF_HDR);
  uint*   rtot    = (uint*)(ws + OFF_RTOT);
  uint*   cnt     = (uint*)(ws + OFF_CNT);
  uint*   hist1   = (uint*)(ws + OFF_H1);
  uint*   base    = (uint*)(ws + OFF_BASE);
  uint*   keyhi   = (uint*)(ws + OFF_KEY);
  u64*    buck    = (u64*) (ws + OFF_BUCK);
  uint*   list    = (uint*)(ws + OFF_LIST);
  float4* boxes6k = (float4*)(ws + OFF_BOX);
  float*  score6k = (float*)(ws + OFF_SCO);
  float*  area6k  = (float*)(ws + OFF_AREA);
  u64*    validW  = (u64*) (ws + OFF_VAL);

  dim3 gN((NN + 255) / 256, BB);
  keys_only<<<gN, 256, 0, stream>>>(props, clsp, keyhi);
  hist_range<<<dim3(NRANGE, BB), 256, 0, stream>>>((const uint4*)keyhi, hist1, rtot, cnt);
  scan128<<<dim3(NRANGE, BB), 256, 0, stream>>>(hist1, rtot, base, hdr, validW);
  bucket_scatter<<<gN, 256, 0, stream>>>(keyhi, base, hdr, buck);
  rank_scatter<<<dim3(SCAP / 256, BB), 256, 0, stream>>>(buck, base, hist1, hdr,
                                                         props, clsp, boxes6k,
                                                         score6k, area6k, validW);
  sup_build_pre<<<dim3(2, PWRD, BB), 256, 0, stream>>>(boxes6k, area6k, validW, cnt, list);
  resolve_pre<<<BB, 1024, 0, stream>>>(cnt, list, validW, score6k, boxes6k, hdr, out);
  sup_build_full<<<dim3((NWRD + WQ - 1) / WQ, NWRD, BB), 256, 0, stream>>>(boxes6k, area6k,
                                                                           validW, hdr, cnt, list);
  resolve_full<<<BB, 1024, 0, stream>>>(cnt, list, validW, score6k, boxes6k, hdr, out);
}